// Round 11
// baseline (111.957 us; speedup 1.0000x reference)
//
#include <hip/hip_runtime.h>
#include <hip/hip_bf16.h>

// Quantum layer: 4 qubits, 2 layers. Everything after the RY(x) encoding is a
// fixed unitary U (weights are batch-constant). Each output q is multilinear
// in (1, cos th_p, sin th_p) per qubit: 81 coefficients per output.
// qsetup (4 blocks) computes C as [4][27] float4 (triple + pad) into d_ws.
//
// Delivery-path ledger (all measured on this problem):
//   per-lane uniform dword VMEM, 324/elem  ~20-22us (R1/R4: VMEM-issue bound
//                                           at ~2.3cy/load, FULL occupancy)
//   LDS broadcast                          ~52us    (R3: 184 VGPR occupancy hole)
//   scalar SMEM (all flavors)              ~42-55us (R6/R7/R9: v_mov tax + lgkm)
//   27-wide asm VGPR batch                 220us    (R8: forced liveness->spill)
//   laundered float4, EPT=4, unbounded RA  ~67us    (R10: RA hoisted 27 float4
//                                           per q -> VGPR=236 -> 2 waves/SIMD)
// This round = R1/R4's winning regime (JIT uniform loads, high occupancy) with
// 3x fewer VMEM instructions: float4 triples (108/elem), laundered base (no
// R7 scalarization), __launch_bounds__(256,8) caps VGPR at 64 so the RA
// CANNOT re-create R10's 27-wide hoist; 8 waves/SIMD hide load latency.

__global__ __launch_bounds__(256) void qsetup(const float* __restrict__ w,
                                              float* __restrict__ C) {
    __shared__ float Ur[16][16];   // [row k][col j]
    __shared__ float Ui[16][16];
    __shared__ float M[16][16];
    const int q = blockIdx.x;      // output qubit 0..3
    const int tid = threadIdx.x;

    // ---- step 1: threads 0..15 each simulate one basis column of U ----
    if (tid < 16) {
        float re[16], im[16];
#pragma unroll
        for (int i = 0; i < 16; ++i) { re[i] = (i == tid) ? 1.0f : 0.0f; im[i] = 0.0f; }

#pragma unroll
        for (int ly = 0; ly < 2; ++ly) {
#pragma unroll
            for (int qq = 0; qq < 4; ++qq) {
                const int mm = 8 >> qq;
                float th, c, s;
                // RX(w[ly][qq][0])
                th = w[(ly * 4 + qq) * 3 + 0] * 0.5f; c = __cosf(th); s = __sinf(th);
#pragma unroll
                for (int i = 0; i < 16; ++i) if (!(i & mm)) {
                    const int j = i | mm;
                    float r0 = re[i], i0 = im[i], r1 = re[j], i1 = im[j];
                    re[i] = c * r0 + s * i1;  im[i] = c * i0 - s * r1;
                    re[j] = s * i0 + c * r1;  im[j] = -s * r0 + c * i1;
                }
                // RY(w[ly][qq][1])
                th = w[(ly * 4 + qq) * 3 + 1] * 0.5f; c = __cosf(th); s = __sinf(th);
#pragma unroll
                for (int i = 0; i < 16; ++i) if (!(i & mm)) {
                    const int j = i | mm;
                    float r0 = re[i], i0 = im[i], r1 = re[j], i1 = im[j];
                    re[i] = c * r0 - s * r1;  im[i] = c * i0 - s * i1;
                    re[j] = s * r0 + c * r1;  im[j] = s * i0 + c * i1;
                }
                // RZ(w[ly][qq][2])
                th = w[(ly * 4 + qq) * 3 + 2] * 0.5f; c = __cosf(th); s = __sinf(th);
#pragma unroll
                for (int i = 0; i < 16; ++i) if (!(i & mm)) {
                    const int j = i | mm;
                    float r0 = re[i], i0 = im[i], r1 = re[j], i1 = im[j];
                    re[i] = c * r0 + s * i0;  im[i] = c * i0 - s * r0;
                    re[j] = c * r1 - s * i1;  im[j] = c * i1 + s * r1;
                }
            }
            // CNOT chain (q,q+1)
#pragma unroll
            for (int qq = 0; qq < 3; ++qq) {
                const int mc = 8 >> qq, mt = 8 >> (qq + 1);
#pragma unroll
                for (int i = 0; i < 16; ++i) if ((i & mc) && !(i & mt)) {
                    const int j = i | mt;
                    float tr = re[i]; re[i] = re[j]; re[j] = tr;
                    float ti = im[i]; im[i] = im[j]; im[j] = ti;
                }
            }
        }
#pragma unroll
        for (int k = 0; k < 16; ++k) { Ur[k][tid] = re[k]; Ui[k][tid] = im[k]; }
    }
    __syncthreads();

    // ---- step 2: M[j][l] = sum_k sign_q(k) Re(U[k,j] conj(U[k,l])) ----
    {
        const int j = tid >> 4, l = tid & 15;
        float acc = 0.0f;
#pragma unroll
        for (int k = 0; k < 16; ++k) {
            const float sgn = ((k >> (3 - q)) & 1) ? -1.0f : 1.0f;
            acc += sgn * (Ur[k][j] * Ur[k][l] + Ui[k][j] * Ui[k][l]);
        }
        M[j][l] = acc;
    }
    __syncthreads();

    // ---- step 3: project onto (1,cos,sin)^{(x)4} basis ----
    // Layout: C[(q*27 + T)*4 + m], T = (i*3+j)*3+k, m = 0..2, m=3 zero pad.
    if (tid < 108) {
        if (tid < 81) {
            int ap[4];
            ap[0] = tid / 27; ap[1] = (tid / 9) % 3; ap[2] = (tid / 3) % 3; ap[3] = tid % 3;
            float acc = 0.0f;
            for (int m = 0; m < 16; ++m) {
                int j = 0, l = 0; float sgn = 1.0f;
#pragma unroll
                for (int p = 0; p < 4; ++p) {
                    const int o = (m >> (3 - p)) & 1;
                    int jb = o, lb = (ap[p] == 2) ? (o ^ 1) : o;
                    if (ap[p] == 1 && o) sgn = -sgn;
                    j = (j << 1) | jb; l = (l << 1) | lb;
                }
                acc += sgn * M[j][l];
            }
            C[(q * 27 + tid / 3) * 4 + (tid % 3)] = acc * 0.0625f;
        } else {
            C[(q * 27 + (tid - 81)) * 4 + 3] = 0.0f;   // pad lane
        }
    }
}

__global__ __launch_bounds__(256, 8) void qmain(const float* __restrict__ x,
                                                const float* __restrict__ C,
                                                float* __restrict__ out, int B) {
    const int b = blockIdx.x * 256 + threadIdx.x;
    if (b >= B) return;

    // ---- x load + transcendentals ----
    const float4 xv = *reinterpret_cast<const float4*>(x + (size_t)b * 8);
    float cg[4], sg[4];
    {
        float xs[4] = {xv.x, xv.y, xv.z, xv.w};
#pragma unroll
        for (int q = 0; q < 4; ++q) {
            const float ex = __expf(2.0f * xs[q]);
            const float t = 1.0f - __fdividef(2.0f, ex + 1.0f);   // tanh(x)
            __sincosf(3.1415f * t, &sg[q], &cg[q]);
        }
    }

    // Launder a zero offset through asm into a VGPR: every coefficient
    // address derives from it, so the compiler cannot prove wave-uniformity
    // and must keep per-lane VMEM float4 loads (blocks R7's SMEM
    // scalarization). Loads are plain C++ and live INSIDE the Horner, and
    // the (256,8) VGPR cap (64) makes R10's 27-wide hoist impossible:
    // the scheduler is forced to just-in-time loads, TLP hides latency.
    int z;
    asm volatile("" : "=v"(z) : "0"(0));
    const float4* __restrict__ cvb = reinterpret_cast<const float4*>(C) + z;

    float ev[4];
#pragma unroll
    for (int q = 0; q < 4; ++q) {
        float acc, ai, aj;
#pragma unroll
        for (int i = 0; i < 3; ++i) {
#pragma unroll
            for (int j = 0; j < 3; ++j) {
#pragma unroll
                for (int k = 0; k < 3; ++k) {
                    const float4 cv = cvb[q * 27 + (i * 3 + j) * 3 + k];
                    float t = __fmaf_rn(cv.y, cg[3], cv.x);
                    t = __fmaf_rn(cv.z, sg[3], t);
                    if (k == 0)      aj = t;
                    else if (k == 1) aj = __fmaf_rn(t, cg[2], aj);
                    else             aj = __fmaf_rn(t, sg[2], aj);
                }
                if (j == 0)      ai = aj;
                else if (j == 1) ai = __fmaf_rn(aj, cg[1], ai);
                else             ai = __fmaf_rn(aj, sg[1], ai);
            }
            if (i == 0)      acc = ai;
            else if (i == 1) acc = __fmaf_rn(ai, cg[0], acc);
            else             acc = __fmaf_rn(ai, sg[0], acc);
        }
        ev[q] = acc;
    }

    *reinterpret_cast<float4*>(out + (size_t)b * 4) =
        make_float4(ev[0], ev[1], ev[2], ev[3]);
}

extern "C" void kernel_launch(void* const* d_in, const int* in_sizes, int n_in,
                              void* d_out, int out_size, void* d_ws, size_t ws_size,
                              hipStream_t stream) {
    const float* x = (const float*)d_in[0];       // (B, 8) f32
    const float* w = (const float*)d_in[1];       // (2, 4, 3) f32
    float* out = (float*)d_out;                   // (B, 4) f32
    float* C = (float*)d_ws;                      // 4*27 float4 scratch

    const int B = in_sizes[0] / 8;

    qsetup<<<4, 256, 0, stream>>>(w, C);
    qmain<<<(B + 255) / 256, 256, 0, stream>>>(x, C, out, B);
}

// Round 12
// 70.135 us; speedup vs baseline: 1.5963x; 1.5963x over previous
//
#include <hip/hip_runtime.h>
#include <hip/hip_bf16.h>

// Quantum layer: 4 qubits, 2 layers. Everything after the RY(x) encoding is a
// fixed unitary U (weights are batch-constant). Each output q is multilinear
// in (1, cos th_p, sin th_p) per qubit: 81 coefficients per output.
// qsetup (4 blocks) computes C as [4][27] float4 (triple + pad) into d_ws.
//
// Delivery model (validated: R1/R4 = 324 broadcast dword loads x 64
// batches/CU x ~2.3cy = 20us, matches measurement): coefficient delivery is
// per-WAVE broadcast; cost = VMEM instrs per 64-elem batch. float4 triples
// cut that to 108 -> ~5us, at the VALU (~5.1us) and HBM (~5.2us) floors.
// Failure ledger: scalar SMEM 42-55us (R6/7/9), LDS 52us (R3), 27-wide asm
// batch spill 220us (R8), free-RA hoist VGPR=236 67us (R10), hard cap
// VGPR=32 spill 123us (R11). Fix: EPT=1 lean skeleton; laundered base
// (blocks scalarization); compiler memory-barrier seams every 9 triples
// bound the hoist window to 36 VGPR -- no cap, RA otherwise free.

__global__ __launch_bounds__(256) void qsetup(const float* __restrict__ w,
                                              float* __restrict__ C) {
    __shared__ float Ur[16][16];   // [row k][col j]
    __shared__ float Ui[16][16];
    __shared__ float M[16][16];
    const int q = blockIdx.x;      // output qubit 0..3
    const int tid = threadIdx.x;

    // ---- step 1: threads 0..15 each simulate one basis column of U ----
    if (tid < 16) {
        float re[16], im[16];
#pragma unroll
        for (int i = 0; i < 16; ++i) { re[i] = (i == tid) ? 1.0f : 0.0f; im[i] = 0.0f; }

#pragma unroll
        for (int ly = 0; ly < 2; ++ly) {
#pragma unroll
            for (int qq = 0; qq < 4; ++qq) {
                const int mm = 8 >> qq;
                float th, c, s;
                // RX(w[ly][qq][0])
                th = w[(ly * 4 + qq) * 3 + 0] * 0.5f; c = __cosf(th); s = __sinf(th);
#pragma unroll
                for (int i = 0; i < 16; ++i) if (!(i & mm)) {
                    const int j = i | mm;
                    float r0 = re[i], i0 = im[i], r1 = re[j], i1 = im[j];
                    re[i] = c * r0 + s * i1;  im[i] = c * i0 - s * r1;
                    re[j] = s * i0 + c * r1;  im[j] = -s * r0 + c * i1;
                }
                // RY(w[ly][qq][1])
                th = w[(ly * 4 + qq) * 3 + 1] * 0.5f; c = __cosf(th); s = __sinf(th);
#pragma unroll
                for (int i = 0; i < 16; ++i) if (!(i & mm)) {
                    const int j = i | mm;
                    float r0 = re[i], i0 = im[i], r1 = re[j], i1 = im[j];
                    re[i] = c * r0 - s * r1;  im[i] = c * i0 - s * i1;
                    re[j] = s * r0 + c * r1;  im[j] = s * i0 + c * i1;
                }
                // RZ(w[ly][qq][2])
                th = w[(ly * 4 + qq) * 3 + 2] * 0.5f; c = __cosf(th); s = __sinf(th);
#pragma unroll
                for (int i = 0; i < 16; ++i) if (!(i & mm)) {
                    const int j = i | mm;
                    float r0 = re[i], i0 = im[i], r1 = re[j], i1 = im[j];
                    re[i] = c * r0 + s * i0;  im[i] = c * i0 - s * r0;
                    re[j] = c * r1 - s * i1;  im[j] = c * i1 + s * r1;
                }
            }
            // CNOT chain (q,q+1)
#pragma unroll
            for (int qq = 0; qq < 3; ++qq) {
                const int mc = 8 >> qq, mt = 8 >> (qq + 1);
#pragma unroll
                for (int i = 0; i < 16; ++i) if ((i & mc) && !(i & mt)) {
                    const int j = i | mt;
                    float tr = re[i]; re[i] = re[j]; re[j] = tr;
                    float ti = im[i]; im[i] = im[j]; im[j] = ti;
                }
            }
        }
#pragma unroll
        for (int k = 0; k < 16; ++k) { Ur[k][tid] = re[k]; Ui[k][tid] = im[k]; }
    }
    __syncthreads();

    // ---- step 2: M[j][l] = sum_k sign_q(k) Re(U[k,j] conj(U[k,l])) ----
    {
        const int j = tid >> 4, l = tid & 15;
        float acc = 0.0f;
#pragma unroll
        for (int k = 0; k < 16; ++k) {
            const float sgn = ((k >> (3 - q)) & 1) ? -1.0f : 1.0f;
            acc += sgn * (Ur[k][j] * Ur[k][l] + Ui[k][j] * Ui[k][l]);
        }
        M[j][l] = acc;
    }
    __syncthreads();

    // ---- step 3: project onto (1,cos,sin)^{(x)4} basis ----
    // Layout: C[(q*27 + T)*4 + m], T = (i*3+j)*3+k, m = 0..2, m=3 zero pad.
    if (tid < 108) {
        if (tid < 81) {
            int ap[4];
            ap[0] = tid / 27; ap[1] = (tid / 9) % 3; ap[2] = (tid / 3) % 3; ap[3] = tid % 3;
            float acc = 0.0f;
            for (int m = 0; m < 16; ++m) {
                int j = 0, l = 0; float sgn = 1.0f;
#pragma unroll
                for (int p = 0; p < 4; ++p) {
                    const int o = (m >> (3 - p)) & 1;
                    int jb = o, lb = (ap[p] == 2) ? (o ^ 1) : o;
                    if (ap[p] == 1 && o) sgn = -sgn;
                    j = (j << 1) | jb; l = (l << 1) | lb;
                }
                acc += sgn * M[j][l];
            }
            C[(q * 27 + tid / 3) * 4 + (tid % 3)] = acc * 0.0625f;
        } else {
            C[(q * 27 + (tid - 81)) * 4 + 3] = 0.0f;   // pad lane
        }
    }
}

__global__ __launch_bounds__(256) void qmain(const float* __restrict__ x,
                                             const float* __restrict__ C,
                                             float* __restrict__ out, int B) {
    const int b = blockIdx.x * 256 + threadIdx.x;
    if (b >= B) return;

    // ---- x load + transcendentals ----
    const float4 xv = *reinterpret_cast<const float4*>(x + (size_t)b * 8);
    float cg[4], sg[4];
    {
        float xs[4] = {xv.x, xv.y, xv.z, xv.w};
#pragma unroll
        for (int q = 0; q < 4; ++q) {
            const float ex = __expf(2.0f * xs[q]);
            const float t = 1.0f - __fdividef(2.0f, ex + 1.0f);   // tanh(x)
            __sincosf(3.1415f * t, &sg[q], &cg[q]);
        }
    }

    // Laundered base: compiler cannot prove the address wave-uniform, so
    // loads stay per-lane VMEM float4 (no SMEM scalarization, R7 failure).
    int z;
    asm volatile("" : "=v"(z) : "0"(0));
    const float4* __restrict__ cvb = reinterpret_cast<const float4*>(C) + z;

    float ev[4];
#pragma unroll
    for (int q = 0; q < 4; ++q) {
        float acc, ai, aj;
#pragma unroll
        for (int i = 0; i < 3; ++i) {
#pragma unroll
            for (int j = 0; j < 3; ++j) {
#pragma unroll
                for (int k = 0; k < 3; ++k) {
                    const float4 cv = cvb[q * 27 + (i * 3 + j) * 3 + k];
                    float t = __fmaf_rn(cv.y, cg[3], cv.x);
                    t = __fmaf_rn(cv.z, sg[3], t);
                    if (k == 0)      aj = t;
                    else if (k == 1) aj = __fmaf_rn(t, cg[2], aj);
                    else             aj = __fmaf_rn(t, sg[2], aj);
                }
                if (j == 0)      ai = aj;
                else if (j == 1) ai = __fmaf_rn(aj, cg[1], ai);
                else             ai = __fmaf_rn(aj, sg[1], ai);
            }
            if (i == 0)      acc = ai;
            else if (i == 1) acc = __fmaf_rn(ai, cg[0], acc);
            else             acc = __fmaf_rn(ai, sg[0], acc);

            // Seam: loads cannot migrate across this compiler barrier, so at
            // most 9 float4 (36 VGPR) are in flight -- bounds the R10 hoist
            // without the R11 hard cap. Registers are unaffected.
            asm volatile("" ::: "memory");
        }
        ev[q] = acc;
    }

    *reinterpret_cast<float4*>(out + (size_t)b * 4) =
        make_float4(ev[0], ev[1], ev[2], ev[3]);
}

extern "C" void kernel_launch(void* const* d_in, const int* in_sizes, int n_in,
                              void* d_out, int out_size, void* d_ws, size_t ws_size,
                              hipStream_t stream) {
    const float* x = (const float*)d_in[0];       // (B, 8) f32
    const float* w = (const float*)d_in[1];       // (2, 4, 3) f32
    float* out = (float*)d_out;                   // (B, 4) f32
    float* C = (float*)d_ws;                      // 4*27 float4 scratch

    const int B = in_sizes[0] / 8;

    qsetup<<<4, 256, 0, stream>>>(w, C);
    qmain<<<(B + 255) / 256, 256, 0, stream>>>(x, C, out, B);
}